// Round 10
// baseline (482.684 us; speedup 1.0000x reference)
//
#include <hip/hip_runtime.h>
#include <hip/hip_bf16.h>

// Problem constants (from reference)
#define NNODES 10000
#define NEDGES 320000
#define INF_   1280
#define HID_   128
#define HEADS_ 4
#define OUTF_  500
#define HC_    512          // HEADS_*HID_
#define NEG_SLOPE 0.2f
#define BN_EPS 1e-5f

typedef __attribute__((ext_vector_type(8))) short short8x;
typedef __attribute__((ext_vector_type(4))) float f32x4;
typedef unsigned short ushort_t;
typedef unsigned int uint_t;

__device__ __forceinline__ ushort_t f2bf(float f) {
    uint_t u = __float_as_uint(f);
    u = (u + 0x7fffu + ((u >> 16) & 1u)) >> 16;   // round-to-nearest-even
    return (ushort_t)u;
}
__device__ __forceinline__ float bf_lo(uint_t p) { return __uint_as_float(p << 16); }
__device__ __forceinline__ float bf_hi(uint_t p) { return __uint_as_float(p & 0xffff0000u); }
__device__ __forceinline__ float lrelu(float x) { return (x >= 0.f) ? x : NEG_SLOPE * x; }
__device__ __forceinline__ float eluf(float x) { return (x > 0.f) ? x : (__expf(x) - 1.0f); }
__device__ __forceinline__ uint_t pack_bf16_rn(float a, float b) {
    __hip_bfloat162 h = __float22bfloat162_rn(make_float2(a, b));  // hw packed cvt, RNE
    return *(uint_t*)&h;
}

// ---------------------------------------------------------------------------
// convall: x->bf16 + 3 weight transposes + zero {counts, L3 logit accs,
// bn_stats fence counters}.
// R3 lesson: no mass cross-XCD atomic accumulators (bypass L2 -> HBM txns).
// R5 lesson: fusion pays only if fused work < removed dispatch gap (~8µs).
// R8 lesson: 64-block scalar-load reduction = latency-starved (55µs, 4.5% occ).
// ---------------------------------------------------------------------------
#define CVX (NNODES * INF_ / 4)        // 3,200,000 float4 chunks of x
#define CN1 (HC_ * INF_)
#define CN2 (HC_ * HC_)
#define CN3 (HC_ * HC_)                // Wt3 (padded rows)
#define CZC (NNODES / 4)               // counts as uint4 (10000 ints = 2500)
#define CZ3 (NNODES / 2 + 1)           // s3+d3 (2*10000 f) + counters (1 uint4)
__global__ void convall_kernel(const float* __restrict__ x,
                               const float* __restrict__ W1,
                               const float* __restrict__ W2,
                               const float* __restrict__ W3,
                               ushort_t* __restrict__ x_bf,
                               ushort_t* __restrict__ Wt1,
                               ushort_t* __restrict__ Wt2,
                               ushort_t* __restrict__ Wt3,
                               uint4* __restrict__ zc,     // counts
                               uint4* __restrict__ zz) {   // s3,d3,counters
    int i = blockIdx.x * blockDim.x + threadIdx.x;
    if (i < CVX) {
        float4 v = ((const float4*)x)[i];
        ((uint2*)x_bf)[i] = make_uint2(pack_bf16_rn(v.x, v.y), pack_bf16_rn(v.z, v.w));
    } else if (i < CVX + CN1) {
        int j = i - CVX;
        int n = j / INF_, k = j - n * INF_;
        Wt1[j] = f2bf(W1[(size_t)k * HC_ + n]);
    } else if (i < CVX + CN1 + CN2) {
        int j = i - CVX - CN1;
        int n = j / HC_, k = j - n * HC_;
        Wt2[j] = f2bf(W2[(size_t)k * HC_ + n]);
    } else if (i < CVX + CN1 + CN2 + CN3) {
        int j = i - CVX - CN1 - CN2;
        int n = j / HC_, k = j - n * HC_;
        Wt3[j] = (n < OUTF_) ? f2bf(W3[(size_t)k * OUTF_ + n]) : (ushort_t)0;
    } else if (i < CVX + CN1 + CN2 + CN3 + CZC) {
        zc[i - CVX - CN1 - CN2 - CN3] = make_uint4(0, 0, 0, 0);
    } else if (i < CVX + CN1 + CN2 + CN3 + CZC + CZ3) {
        zz[i - CVX - CN1 - CN2 - CN3 - CZC] = make_uint4(0, 0, 0, 0);
    }
}

// ---------------------------------------------------------------------------
// CSR build (by destination)
// ---------------------------------------------------------------------------
__global__ void count_kernel(const int* __restrict__ dst, int* __restrict__ counts, int E) {
    int e = blockIdx.x * blockDim.x + threadIdx.x;
    if (e < E) atomicAdd(&counts[dst[e]], 1);
}

// single-workgroup scan, wave-shuffle version: 2 barriers.
__global__ __launch_bounds__(1024) void scan_fused_kernel(const int* __restrict__ counts,
                                                          int* __restrict__ offsets,
                                                          int* __restrict__ cursor, int n) {
    __shared__ int wsum[16];
    int t = threadIdx.x;
    int lane = t & 63, wv = t >> 6;
    int base = t * 10;
    int v[10];
    int s = 0;
#pragma unroll
    for (int k = 0; k < 10; ++k) {
        int i = base + k;
        int c = (i < n) ? counts[i] : 0;
        v[k] = s;              // exclusive within-thread prefix
        s += c;
    }
    // inclusive wave scan of per-thread sums
    int incl = s;
#pragma unroll
    for (int off = 1; off < 64; off <<= 1) {
        int u = __shfl_up(incl, off, 64);
        if (lane >= off) incl += u;
    }
    if (lane == 63) wsum[wv] = incl;
    __syncthreads();
    if (t < 16) {
        int ws = wsum[t];
        int in2 = ws;
#pragma unroll
        for (int off = 1; off < 16; off <<= 1) {
            int u = __shfl_up(in2, off, 64);
            if (t >= off) in2 += u;
        }
        wsum[t] = in2 - ws;    // exclusive wave prefix
    }
    __syncthreads();
    int basep = wsum[wv] + (incl - s);
#pragma unroll
    for (int k = 0; k < 10; ++k) {
        int i = base + k;
        if (i < n) {
            int o = basep + v[k];
            offsets[i] = o;
            cursor[i] = o;
        }
    }
    if (t == 1023) offsets[n] = basep + s;
}

__global__ void scatter_kernel(const int* __restrict__ src, const int* __restrict__ dst,
                               int* __restrict__ cursor, int* __restrict__ esrc, int E) {
    int e = blockIdx.x * blockDim.x + threadIdx.x;
    if (e < E) {
        int p = atomicAdd(&cursor[dst[e]], 1);
        esrc[p] = src[e];
    }
}

// ---------------------------------------------------------------------------
// bf16 MFMA GEMM + fused logits epilogue (+ optional fused BN-apply+ELU on A).
// R6/R7: latency-bound (grid 628 = 2.4 blocks/CU) -> depth-2 reg prefetch +
// bijective XCD-chunk swizzle (A row-panel's 4 col-tiles share one L2).
// BNA: A is hbuf f32; staging applies v*scale+shift, ELU, packs bf16 -> LDS.
// ---------------------------------------------------------------------------
#define LDT 40

template<int LOGIT, bool BNA>
__global__ __launch_bounds__(256) void gemm_kernel(
    const void* __restrict__ Ain,      // [M][K] bf16, or f32 when BNA
    const ushort_t* __restrict__ Bt,   // [512][K] bf16 (transposed, padded)
    ushort_t* __restrict__ Cb,         // [M][512] bf16
    const float* __restrict__ bnsc,    // [K] scale (BNA)
    const float* __restrict__ bnsh,    // [K] shift (BNA)
    const float* __restrict__ aS,      // flat [HC] (L1/L2) or [OUTF] (L3)
    const float* __restrict__ aD,
    float* __restrict__ s_log,         // [N][LOGIT]
    float* __restrict__ d_log,
    int M, int K)
{
    __shared__ __align__(16) ushort_t As[64 * LDT];
    __shared__ __align__(16) ushort_t Bs[128 * LDT];
    __shared__ float sred[64][2], dred[64][2];

    // bijective XCD-chunk swizzle (nblk=628: q=78, r=4)
    int nblk = gridDim.x;
    int orig = blockIdx.x;
    int q = nblk >> 3, r = nblk & 7;
    int xcd = orig & 7;
    int lid = (xcd < r ? xcd * (q + 1) : r * (q + 1) + (xcd - r) * q) + (orig >> 3);
    int m0 = (lid >> 2) * 64;     // row panel (consecutive lids share it)
    int n0 = (lid & 3) * 128;

    int tid  = threadIdx.x;
    int lane = tid & 63;
    int w    = tid >> 6;
    int wm   = (w & 1) * 32;       // wave m-offset
    int wn   = (w >> 1) * 64;      // wave n-offset
    int quad = lane >> 4;
    int c16  = lane & 15;

    f32x4 acc[2][4];
#pragma unroll
    for (int i = 0; i < 2; ++i)
#pragma unroll
        for (int j = 0; j < 4; ++j)
#pragma unroll
            for (int r2 = 0; r2 < 4; ++r2) acc[i][j][r2] = 0.0f;

    // staging coords
    int sr = tid >> 2;              // A row 0..63
    int sk = (tid & 3) * 8;         // A k-chunk (8 channels)
    int gm = m0 + sr;  if (gm > M - 1) gm = M - 1;
    const ushort_t* aptr  = nullptr;
    const float*    aptrf = nullptr;
    if (BNA) aptrf = (const float*)Ain + (size_t)gm * K + sk;
    else     aptr  = (const ushort_t*)Ain + (size_t)gm * K + sk;
    int br0 = tid >> 2;             // B rows (2 chunks/thread)
    int bk0 = (tid & 3) * 8;
    int br1 = (256 + tid) >> 2;
    int bk1 = bk0;
    const ushort_t* bptr0 = Bt + (size_t)(n0 + br0) * K + bk0;
    const ushort_t* bptr1 = Bt + (size_t)(n0 + br1) * K + bk1;

    // depth-2 prefetch registers
    uint4 av_a, av_b;
    float4 fa0_a, fa1_a, fa0_b, fa1_b;
    if (BNA) {
        fa0_a = *(const float4*)(aptrf);
        fa1_a = *(const float4*)(aptrf + 4);
        if (K > 32) {
            fa0_b = *(const float4*)(aptrf + 32);
            fa1_b = *(const float4*)(aptrf + 36);
        }
    } else {
        av_a = *(const uint4*)(aptr);
        if (K > 32) av_b = *(const uint4*)(aptr + 32);
    }
    uint4 bv0_a = *(const uint4*)(bptr0);
    uint4 bv1_a = *(const uint4*)(bptr1);
    uint4 bv0_b, bv1_b;
    if (K > 32) {
        bv0_b = *(const uint4*)(bptr0 + 32);
        bv1_b = *(const uint4*)(bptr1 + 32);
    }

    for (int k0 = 0; k0 < K; k0 += 32) {
        if (BNA) {
            int cb = k0 + sk;       // this iteration's channel base (L1-hot)
            float4 sc0 = *(const float4*)(bnsc + cb);
            float4 sc1 = *(const float4*)(bnsc + cb + 4);
            float4 sh0 = *(const float4*)(bnsh + cb);
            float4 sh1 = *(const float4*)(bnsh + cb + 4);
            float v0 = eluf(fa0_a.x * sc0.x + sh0.x);
            float v1 = eluf(fa0_a.y * sc0.y + sh0.y);
            float v2 = eluf(fa0_a.z * sc0.z + sh0.z);
            float v3 = eluf(fa0_a.w * sc0.w + sh0.w);
            float v4 = eluf(fa1_a.x * sc1.x + sh1.x);
            float v5 = eluf(fa1_a.y * sc1.y + sh1.y);
            float v6 = eluf(fa1_a.z * sc1.z + sh1.z);
            float v7 = eluf(fa1_a.w * sc1.w + sh1.w);
            *(uint4*)&As[sr * LDT + sk] = make_uint4(
                pack_bf16_rn(v0, v1), pack_bf16_rn(v2, v3),
                pack_bf16_rn(v4, v5), pack_bf16_rn(v6, v7));
        } else {
            *(uint4*)&As[sr * LDT + sk] = av_a;
        }
        *(uint4*)&Bs[br0 * LDT + bk0] = bv0_a;
        *(uint4*)&Bs[br1 * LDT + bk1] = bv1_a;
        __syncthreads();

        short8x af0 = *(const short8x*)&As[(wm +      c16) * LDT + quad * 8];
        short8x af1 = *(const short8x*)&As[(wm + 16 + c16) * LDT + quad * 8];
        short8x bf[4];
#pragma unroll
        for (int nt = 0; nt < 4; ++nt)
            bf[nt] = *(const short8x*)&Bs[(wn + nt * 16 + c16) * LDT + quad * 8];

        // shift pipeline; issue k+2's loads (~2 iterations in flight)
        if (BNA) {
            fa0_a = fa0_b; fa1_a = fa1_b;
            if (k0 + 64 < K) {
                fa0_b = *(const float4*)(aptrf + k0 + 64);
                fa1_b = *(const float4*)(aptrf + k0 + 68);
            }
        } else {
            av_a = av_b;
            if (k0 + 64 < K) av_b = *(const uint4*)(aptr + k0 + 64);
        }
        bv0_a = bv0_b; bv1_a = bv1_b;
        if (k0 + 64 < K) {
            bv0_b = *(const uint4*)(bptr0 + k0 + 64);
            bv1_b = *(const uint4*)(bptr1 + k0 + 64);
        }

#pragma unroll
        for (int nt = 0; nt < 4; ++nt) {
            acc[0][nt] = __builtin_amdgcn_mfma_f32_16x16x32_bf16(af0, bf[nt], acc[0][nt], 0, 0, 0);
            acc[1][nt] = __builtin_amdgcn_mfma_f32_16x16x32_bf16(af1, bf[nt], acc[1][nt], 0, 0, 0);
        }
        __syncthreads();
    }

    // ---- C store ----
#pragma unroll
    for (int mt = 0; mt < 2; ++mt) {
#pragma unroll
        for (int r2 = 0; r2 < 4; ++r2) {
            int row = m0 + wm + mt * 16 + quad * 4 + r2;
            if (row < M) {
#pragma unroll
                for (int nt = 0; nt < 4; ++nt) {
                    int col = n0 + wn + nt * 16 + c16;
                    Cb[(size_t)row * 512 + col] = f2bf(acc[mt][nt][r2]);
                }
            }
        }
    }

    // ---- fused logits epilogue ----
    float as_[4], ad_[4];
#pragma unroll
    for (int nt = 0; nt < 4; ++nt) {
        int colg = n0 + wn + nt * 16 + c16;     // global output column
        if (LOGIT == 4) {
            as_[nt] = aS[colg];                  // a_src flat over HC == col index
            ad_[nt] = aD[colg];
        } else {
            as_[nt] = (colg < OUTF_) ? aS[colg] : 0.f;
            ad_[nt] = (colg < OUTF_) ? aD[colg] : 0.f;
        }
    }
#pragma unroll
    for (int mt = 0; mt < 2; ++mt) {
#pragma unroll
        for (int r2 = 0; r2 < 4; ++r2) {
            float ps = acc[mt][0][r2] * as_[0] + acc[mt][1][r2] * as_[1]
                     + acc[mt][2][r2] * as_[2] + acc[mt][3][r2] * as_[3];
            float pd = acc[mt][0][r2] * ad_[0] + acc[mt][1][r2] * ad_[1]
                     + acc[mt][2][r2] * ad_[2] + acc[mt][3][r2] * ad_[3];
#pragma unroll
            for (int off = 1; off < 16; off <<= 1) {
                ps += __shfl_xor(ps, off);
                pd += __shfl_xor(pd, off);
            }
            if (c16 == 0) {
                int rl = wm + mt * 16 + quad * 4 + r2;   // 0..63
                sred[rl][wn >> 6] = ps;
                dred[rl][wn >> 6] = pd;
            }
        }
    }
    __syncthreads();
    if (tid < 64) {
        int row = m0 + tid;
        if (row < M) {
            float s = sred[tid][0] + sred[tid][1];
            float d = dred[tid][0] + dred[tid][1];
            if (LOGIT == 4) {
                int h = n0 >> 7;                 // block col-tile == head
                s_log[row * 4 + h] = s;
                d_log[row * 4 + h] = d;
            } else {
                atomicAdd(&s_log[row], s);
                atomicAdd(&d_log[row], d);
            }
        }
    }
}

// ---------------------------------------------------------------------------
// FUSED softmax+gather (no BN epilogue — R3 lesson).
//   out = (x_self + Σ_j w_j x_{src_j}) / (1 + Σ_j w_j),
//   w_j = exp(lrelu(s[src_j]+d[n]) - c0),  c0 = self logit (shift; w_self=1).
// Slicing (proven): slice pinned per XCD pair, 2.56 MB L2-resident.
// ---------------------------------------------------------------------------
__device__ __forceinline__ void acc8(float* acc, uint4 q, float w) {
    acc[0] += w * bf_lo(q.x); acc[1] += w * bf_hi(q.x);
    acc[2] += w * bf_lo(q.y); acc[3] += w * bf_hi(q.y);
    acc[4] += w * bf_lo(q.z); acc[5] += w * bf_hi(q.z);
    acc[6] += w * bf_lo(q.w); acc[7] += w * bf_hi(q.w);
}

template<int H>
__global__ __launch_bounds__(256) void gather_fused_kernel(
    const uint4* __restrict__ xpb4,     // [node][64]
    const int* __restrict__ offsets, const int* __restrict__ esrc,
    const float* __restrict__ s_log,    // [node][H]
    const float* __restrict__ d_log,    // [node][H]
    const float* __restrict__ bias,     // [OUTC]
    float* __restrict__ out,            // [node][ldo]
    int OUTC, int ldo)
{
    int id = blockIdx.x;
    int xcd = id & 7;
    int slice = xcd >> 1;                       // 0..3 — pinned per XCD pair
    int sub2 = xcd & 1;
    int wv = threadIdx.x >> 6;
    int node = (id >> 3) * 8 + sub2 * 4 + wv;
    if (node >= NNODES) return;
    int lane = threadIdx.x & 63;
    int esub = lane >> 4;                       // edge subgroup 0..3
    int l16 = lane & 15;
    int h = (H == 4) ? slice : 0;
    int rowoff = slice * 16 + l16;              // uint4 index within 64-wide row

    // node-constant attention terms
    float dh = d_log[node * H + h];
    float c0 = lrelu(s_log[node * H + h] + dh); // self-loop logit = shift

    float acc[8];
    float z;
    if (esub == 0) {
        // self loop: w = exp(c0 - c0) = 1
        uint4 p = xpb4[(size_t)node * 64 + rowoff];
        acc[0] = bf_lo(p.x); acc[1] = bf_hi(p.x);
        acc[2] = bf_lo(p.y); acc[3] = bf_hi(p.y);
        acc[4] = bf_lo(p.z); acc[5] = bf_hi(p.z);
        acc[6] = bf_lo(p.w); acc[7] = bf_hi(p.w);
        z = 1.0f;
    } else {
#pragma unroll
        for (int k = 0; k < 8; ++k) acc[k] = 0.f;
        z = 0.f;
    }

    int e0 = offsets[node], e1 = offsets[node + 1];
    int j = e0 + esub;
    for (; j + 12 < e1; j += 16) {
        int s0 = esrc[j], s1 = esrc[j + 4], s2 = esrc[j + 8], s3 = esrc[j + 12];
        uint4 q0 = xpb4[(size_t)s0 * 64 + rowoff];
        uint4 q1 = xpb4[(size_t)s1 * 64 + rowoff];
        uint4 q2 = xpb4[(size_t)s2 * 64 + rowoff];
        uint4 q3 = xpb4[(size_t)s3 * 64 + rowoff];
        float w0 = __expf(lrelu(s_log[s0 * H + h] + dh) - c0);
        float w1 = __expf(lrelu(s_log[s1 * H + h] + dh) - c0);
        float w2 = __expf(lrelu(s_log[s2 * H + h] + dh) - c0);
        float w3 = __expf(lrelu(s_log[s3 * H + h] + dh) - c0);
        acc8(acc, q0, w0);
        acc8(acc, q1, w1);
        acc8(acc, q2, w2);
        acc8(acc, q3, w3);
        z += w0 + w1 + w2 + w3;
    }
    for (; j < e1; j += 4) {
        int s0 = esrc[j];
        uint4 q0 = xpb4[(size_t)s0 * 64 + rowoff];
        float w0 = __expf(lrelu(s_log[s0 * H + h] + dh) - c0);
        acc8(acc, q0, w0);
        z += w0;
    }

    // combine the 4 edge subgroups
#pragma unroll
    for (int k = 0; k < 8; ++k) {
        acc[k] += __shfl_xor(acc[k], 16);
        acc[k] += __shfl_xor(acc[k], 32);
    }
    z += __shfl_xor(z, 16);
    z += __shfl_xor(z, 32);

    if (esub == 0) {
        float zi = 1.0f / z;
        int cbase = slice * 128 + l16 * 8;
        size_t ob = (size_t)node * ldo + cbase;
        if (cbase + 7 < OUTC) {
            float4 o0 = make_float4(acc[0] * zi + bias[cbase + 0], acc[1] * zi + bias[cbase + 1],
                                    acc[2] * zi + bias[cbase + 2], acc[3] * zi + bias[cbase + 3]);
            float4 o1 = make_float4(acc[4] * zi + bias[cbase + 4], acc[5] * zi + bias[cbase + 5],
                                    acc[6] * zi + bias[cbase + 6], acc[7] * zi + bias[cbase + 7]);
            *(float4*)(out + ob) = o0;
            *(float4*)(out + ob + 4) = o1;
        } else {
#pragma unroll
            for (int k = 0; k < 8; ++k) {
                int c = cbase + k;
                if (c < OUTC) out[ob + k] = acc[k] * zi + bias[c];
            }
        }
    }
}

// ---------------------------------------------------------------------------
// BN stats — R8 fix: 256 blocks x 512 threads (full-GPU), unroll-4 MLP,
// non-atomic block-owned partials [256][512], ticket last-block finalize
// (512 threads x 256-bank unroll-8 reduce) -> scale/shift.
// ---------------------------------------------------------------------------
#define BNB 256     // stats blocks (= partial banks)

__global__ __launch_bounds__(512) void bn_stats_kernel(const float* __restrict__ h,
                                                       float* __restrict__ psum,
                                                       float* __restrict__ psumsq,
                                                       const float* __restrict__ gamma,
                                                       const float* __restrict__ beta,
                                                       float* __restrict__ scale,
                                                       float* __restrict__ shift,
                                                       uint_t* __restrict__ counter) {
    int c = threadIdx.x;  // 512 = one channel
    int b = blockIdx.x;   // BNB
    float sm = 0.f, sq = 0.f;
#pragma unroll 4
    for (int r2 = b; r2 < NNODES; r2 += BNB) {
        float v = h[(size_t)r2 * 512 + c];
        sm += v;
        sq += v * v;
    }
    psum[b * 512 + c] = sm;
    psumsq[b * 512 + c] = sq;

    __threadfence();                 // release: partials visible device-wide
    __syncthreads();                 // all threads of this block fenced
    __shared__ uint_t ticket;
    if (c == 0) ticket = atomicAdd(counter, 1u);
    __syncthreads();
    if (ticket == BNB - 1) {         // last block: finalize
        __threadfence();             // acquire
        float s = 0.f, q2 = 0.f;
#pragma unroll 8
        for (int k = 0; k < BNB; ++k) {
            s  += psum[k * 512 + c];
            q2 += psumsq[k * 512 + c];
        }
        const float invN = 1.0f / (float)NNODES;
        float mu = s * invN;
        float var = q2 * invN - mu * mu;
        float sc = gamma[c] * rsqrtf(var + BN_EPS);
        scale[c] = sc;
        shift[c] = beta[c] - mu * sc;
    }
}

// ---------------------------------------------------------------------------
// launch — 12 dispatches
// ---------------------------------------------------------------------------
extern "C" void kernel_launch(void* const* d_in, const int* in_sizes, int n_in,
                              void* d_out, int out_size, void* d_ws, size_t ws_size,
                              hipStream_t stream) {
    const float* x      = (const float*)d_in[0];
    const int*   ei     = (const int*)d_in[1];
    const float* W1     = (const float*)d_in[2];
    const float* a_src1 = (const float*)d_in[3];
    const float* a_dst1 = (const float*)d_in[4];
    const float* b1     = (const float*)d_in[5];
    const float* g1     = (const float*)d_in[6];
    const float* be1    = (const float*)d_in[7];
    const float* W2     = (const float*)d_in[8];
    const float* a_src2 = (const float*)d_in[9];
    const float* a_dst2 = (const float*)d_in[10];
    const float* b2     = (const float*)d_in[11];
    const float* g2     = (const float*)d_in[12];
    const float* be2    = (const float*)d_in[13];
    const float* W3     = (const float*)d_in[14];
    const float* a_src3 = (const float*)d_in[15];
    const float* a_dst3 = (const float*)d_in[16];
    const float* b3     = (const float*)d_in[17];
    float* out = (float*)d_out;

    const int* e_src = ei;           // edge_index[0]
    const int* e_dst = ei + NEDGES;  // edge_index[1]

    // ---- workspace layout ----
    char* w = (char*)d_ws;
    ushort_t* x_bf = (ushort_t*)w;
    float*    hbuf = (float*)w;                               // alias after L1 GEMM
    w += (size_t)NNODES * INF_ * sizeof(ushort_t);            // 25.6 MB
    uint_t* xpb = (uint_t*)w;  w += (size_t)NNODES * HC_ * sizeof(ushort_t);
    ushort_t* Wt1 = (ushort_t*)w; w += (size_t)HC_ * INF_ * sizeof(ushort_t);
    ushort_t* Wt2 = (ushort_t*)w; w += (size_t)HC_ * HC_ * sizeof(ushort_t);
    ushort_t* Wt3 = (ushort_t*)w; w += (size_t)HC_ * HC_ * sizeof(ushort_t);
    int* counts  = (int*)w;    w += NNODES * sizeof(int);
    float* s_log = (float*)w;  w += NNODES * HEADS_ * sizeof(float);
    float* d_log = (float*)w;  w += NNODES * HEADS_ * sizeof(float);
    float* s3_log = (float*)w; w += NNODES * sizeof(float);   // contiguous zero range
    float* d3_log = (float*)w; w += NNODES * sizeof(float);
    uint_t* counters = (uint_t*)w; w += 4 * sizeof(uint_t);   // 2 used, 16B aligned
    float* bnscale = (float*)w; w += HC_ * sizeof(float);
    float* bnshift = (float*)w; w += HC_ * sizeof(float);
    float* psum  = (float*)w;  w += (size_t)BNB * HC_ * sizeof(float);
    float* psumsq= (float*)w;  w += (size_t)BNB * HC_ * sizeof(float);
    int* offsets = (int*)w;    w += (NNODES + 1) * sizeof(int);
    int* cursor  = (int*)w;    w += NNODES * sizeof(int);
    int* esrc    = (int*)w;    w += NEDGES * sizeof(int);

    const int ggBlocks = (HC_ / 128) * ((NNODES + 63) / 64);   // 628, 1-D + swizzle
    const int gaGrid = ((NNODES + 7) / 8) * 8;       // 10000 (sliced gather)

    {
        int TOT = CVX + CN1 + CN2 + CN3 + CZC + CZ3;
        convall_kernel<<<(TOT + 255) / 256, 256, 0, stream>>>(x, W1, W2, W3,
            x_bf, Wt1, Wt2, Wt3, (uint4*)counts, (uint4*)s3_log);
    }
    count_kernel<<<(NEDGES + 255) / 256, 256, 0, stream>>>(e_dst, counts, NEDGES);
    scan_fused_kernel<<<1, 1024, 0, stream>>>(counts, offsets, cursor, NNODES);
    scatter_kernel<<<(NEDGES + 255) / 256, 256, 0, stream>>>(e_src, e_dst, cursor, esrc, NEDGES);

    // ---- Layer 1 ----
    gemm_kernel<4, false><<<ggBlocks, 256, 0, stream>>>(x_bf, Wt1, (ushort_t*)xpb,
        nullptr, nullptr, a_src1, a_dst1, s_log, d_log, NNODES, INF_);
    gather_fused_kernel<HEADS_><<<gaGrid, 256, 0, stream>>>((const uint4*)xpb, offsets, esrc,
        s_log, d_log, b1, hbuf, HC_, HC_);
    bn_stats_kernel<<<BNB, 512, 0, stream>>>(hbuf, psum, psumsq, g1, be1,
        bnscale, bnshift, &counters[0]);

    // ---- Layer 2 (BN1+ELU applied inline on A staging) ----
    gemm_kernel<4, true><<<ggBlocks, 256, 0, stream>>>(hbuf, Wt2, (ushort_t*)xpb,
        bnscale, bnshift, a_src2, a_dst2, s_log, d_log, NNODES, HC_);
    gather_fused_kernel<HEADS_><<<gaGrid, 256, 0, stream>>>((const uint4*)xpb, offsets, esrc,
        s_log, d_log, b2, hbuf, HC_, HC_);
    bn_stats_kernel<<<BNB, 512, 0, stream>>>(hbuf, psum, psumsq, g2, be2,
        bnscale, bnshift, &counters[1]);

    // ---- Layer 3 (H=1, N=500; BN2+ELU inline; logits accumulate into zeroed s3/d3) ----
    gemm_kernel<1, true><<<ggBlocks, 256, 0, stream>>>(hbuf, Wt3, (ushort_t*)xpb,
        bnscale, bnshift, a_src3, a_dst3, s3_log, d3_log, NNODES, HC_);
    gather_fused_kernel<1><<<gaGrid, 256, 0, stream>>>((const uint4*)xpb, offsets, esrc,
        s3_log, d3_log, b3, out, OUTF_, OUTF_);
}

// Round 11
// 381.023 us; speedup vs baseline: 1.2668x; 1.2668x over previous
//
#include <hip/hip_runtime.h>
#include <hip/hip_bf16.h>

// Problem constants (from reference)
#define NNODES 10000
#define NEDGES 320000
#define INF_   1280
#define HID_   128
#define HEADS_ 4
#define OUTF_  500
#define HC_    512          // HEADS_*HID_
#define NEG_SLOPE 0.2f
#define BN_EPS 1e-5f

typedef __attribute__((ext_vector_type(8))) short short8x;
typedef __attribute__((ext_vector_type(4))) float f32x4;
typedef unsigned short ushort_t;
typedef unsigned int uint_t;

__device__ __forceinline__ ushort_t f2bf(float f) {
    uint_t u = __float_as_uint(f);
    u = (u + 0x7fffu + ((u >> 16) & 1u)) >> 16;   // round-to-nearest-even
    return (ushort_t)u;
}
__device__ __forceinline__ float bf_lo(uint_t p) { return __uint_as_float(p << 16); }
__device__ __forceinline__ float bf_hi(uint_t p) { return __uint_as_float(p & 0xffff0000u); }
__device__ __forceinline__ float lrelu(float x) { return (x >= 0.f) ? x : NEG_SLOPE * x; }
__device__ __forceinline__ float eluf(float x) { return (x > 0.f) ? x : (__expf(x) - 1.0f); }
__device__ __forceinline__ uint_t pack_bf16_rn(float a, float b) {
    __hip_bfloat162 h = __float22bfloat162_rn(make_float2(a, b));  // hw packed cvt, RNE
    return *(uint_t*)&h;
}

// ---------------------------------------------------------------------------
// convall: x->bf16 + 3 weight transposes + zero {counts, L3 logit accs}.
// R3 lesson: no mass cross-XCD atomic accumulators (bypass L2 -> HBM txns).
// R5 lesson: fusion pays only if fused work < removed dispatch gap (~8µs).
// R8 lesson: 64-block scalar-load reduction = latency-starved.
// R10 lesson: per-block device-scope __threadfence = L2 writeback drain
//   (non-coherent per-XCD L2); fence+ticket single-kernel reductions lose to
//   a separate dispatch — the kernel boundary IS the fence (~8µs).
// ---------------------------------------------------------------------------
#define CVX (NNODES * INF_ / 4)        // 3,200,000 float4 chunks of x
#define CN1 (HC_ * INF_)
#define CN2 (HC_ * HC_)
#define CN3 (HC_ * HC_)                // Wt3 (padded rows)
#define CZC (NNODES / 4)               // counts as uint4 (10000 ints = 2500)
#define CZ3 (NNODES / 2)               // s3+d3 (2*10000 floats) as uint4
__global__ void convall_kernel(const float* __restrict__ x,
                               const float* __restrict__ W1,
                               const float* __restrict__ W2,
                               const float* __restrict__ W3,
                               ushort_t* __restrict__ x_bf,
                               ushort_t* __restrict__ Wt1,
                               ushort_t* __restrict__ Wt2,
                               ushort_t* __restrict__ Wt3,
                               uint4* __restrict__ zc,     // counts
                               uint4* __restrict__ zz) {   // s3,d3
    int i = blockIdx.x * blockDim.x + threadIdx.x;
    if (i < CVX) {
        float4 v = ((const float4*)x)[i];
        ((uint2*)x_bf)[i] = make_uint2(pack_bf16_rn(v.x, v.y), pack_bf16_rn(v.z, v.w));
    } else if (i < CVX + CN1) {
        int j = i - CVX;
        int n = j / INF_, k = j - n * INF_;
        Wt1[j] = f2bf(W1[(size_t)k * HC_ + n]);
    } else if (i < CVX + CN1 + CN2) {
        int j = i - CVX - CN1;
        int n = j / HC_, k = j - n * HC_;
        Wt2[j] = f2bf(W2[(size_t)k * HC_ + n]);
    } else if (i < CVX + CN1 + CN2 + CN3) {
        int j = i - CVX - CN1 - CN2;
        int n = j / HC_, k = j - n * HC_;
        Wt3[j] = (n < OUTF_) ? f2bf(W3[(size_t)k * OUTF_ + n]) : (ushort_t)0;
    } else if (i < CVX + CN1 + CN2 + CN3 + CZC) {
        zc[i - CVX - CN1 - CN2 - CN3] = make_uint4(0, 0, 0, 0);
    } else if (i < CVX + CN1 + CN2 + CN3 + CZC + CZ3) {
        zz[i - CVX - CN1 - CN2 - CN3 - CZC] = make_uint4(0, 0, 0, 0);
    }
}

// ---------------------------------------------------------------------------
// CSR build (by destination)
// ---------------------------------------------------------------------------
__global__ void count_kernel(const int* __restrict__ dst, int* __restrict__ counts, int E) {
    int e = blockIdx.x * blockDim.x + threadIdx.x;
    if (e < E) atomicAdd(&counts[dst[e]], 1);
}

// single-workgroup scan, wave-shuffle version: 2 barriers.
__global__ __launch_bounds__(1024) void scan_fused_kernel(const int* __restrict__ counts,
                                                          int* __restrict__ offsets,
                                                          int* __restrict__ cursor, int n) {
    __shared__ int wsum[16];
    int t = threadIdx.x;
    int lane = t & 63, wv = t >> 6;
    int base = t * 10;
    int v[10];
    int s = 0;
#pragma unroll
    for (int k = 0; k < 10; ++k) {
        int i = base + k;
        int c = (i < n) ? counts[i] : 0;
        v[k] = s;              // exclusive within-thread prefix
        s += c;
    }
    // inclusive wave scan of per-thread sums
    int incl = s;
#pragma unroll
    for (int off = 1; off < 64; off <<= 1) {
        int u = __shfl_up(incl, off, 64);
        if (lane >= off) incl += u;
    }
    if (lane == 63) wsum[wv] = incl;
    __syncthreads();
    if (t < 16) {
        int ws = wsum[t];
        int in2 = ws;
#pragma unroll
        for (int off = 1; off < 16; off <<= 1) {
            int u = __shfl_up(in2, off, 64);
            if (t >= off) in2 += u;
        }
        wsum[t] = in2 - ws;    // exclusive wave prefix
    }
    __syncthreads();
    int basep = wsum[wv] + (incl - s);
#pragma unroll
    for (int k = 0; k < 10; ++k) {
        int i = base + k;
        if (i < n) {
            int o = basep + v[k];
            offsets[i] = o;
            cursor[i] = o;
        }
    }
    if (t == 1023) offsets[n] = basep + s;
}

__global__ void scatter_kernel(const int* __restrict__ src, const int* __restrict__ dst,
                               int* __restrict__ cursor, int* __restrict__ esrc, int E) {
    int e = blockIdx.x * blockDim.x + threadIdx.x;
    if (e < E) {
        int p = atomicAdd(&cursor[dst[e]], 1);
        esrc[p] = src[e];
    }
}

// ---------------------------------------------------------------------------
// bf16 MFMA GEMM + fused logits epilogue (+ optional fused BN-apply+ELU on A).
// R6/R7: latency-bound (grid 628 = 2.4 blocks/CU) -> depth-2 reg prefetch +
// bijective XCD-chunk swizzle (A row-panel's 4 col-tiles share one L2).
// BNA: A is hbuf f32; staging applies v*scale+shift, ELU, packs bf16 -> LDS.
// ---------------------------------------------------------------------------
#define LDT 40

template<int LOGIT, bool BNA>
__global__ __launch_bounds__(256) void gemm_kernel(
    const void* __restrict__ Ain,      // [M][K] bf16, or f32 when BNA
    const ushort_t* __restrict__ Bt,   // [512][K] bf16 (transposed, padded)
    ushort_t* __restrict__ Cb,         // [M][512] bf16
    const float* __restrict__ bnsc,    // [K] scale (BNA)
    const float* __restrict__ bnsh,    // [K] shift (BNA)
    const float* __restrict__ aS,      // flat [HC] (L1/L2) or [OUTF] (L3)
    const float* __restrict__ aD,
    float* __restrict__ s_log,         // [N][LOGIT]
    float* __restrict__ d_log,
    int M, int K)
{
    __shared__ __align__(16) ushort_t As[64 * LDT];
    __shared__ __align__(16) ushort_t Bs[128 * LDT];
    __shared__ float sred[64][2], dred[64][2];

    // bijective XCD-chunk swizzle (nblk=628: q=78, r=4)
    int nblk = gridDim.x;
    int orig = blockIdx.x;
    int q = nblk >> 3, r = nblk & 7;
    int xcd = orig & 7;
    int lid = (xcd < r ? xcd * (q + 1) : r * (q + 1) + (xcd - r) * q) + (orig >> 3);
    int m0 = (lid >> 2) * 64;     // row panel (consecutive lids share it)
    int n0 = (lid & 3) * 128;

    int tid  = threadIdx.x;
    int lane = tid & 63;
    int w    = tid >> 6;
    int wm   = (w & 1) * 32;       // wave m-offset
    int wn   = (w >> 1) * 64;      // wave n-offset
    int quad = lane >> 4;
    int c16  = lane & 15;

    f32x4 acc[2][4];
#pragma unroll
    for (int i = 0; i < 2; ++i)
#pragma unroll
        for (int j = 0; j < 4; ++j)
#pragma unroll
            for (int r2 = 0; r2 < 4; ++r2) acc[i][j][r2] = 0.0f;

    // staging coords
    int sr = tid >> 2;              // A row 0..63
    int sk = (tid & 3) * 8;         // A k-chunk (8 channels)
    int gm = m0 + sr;  if (gm > M - 1) gm = M - 1;
    const ushort_t* aptr  = nullptr;
    const float*    aptrf = nullptr;
    if (BNA) aptrf = (const float*)Ain + (size_t)gm * K + sk;
    else     aptr  = (const ushort_t*)Ain + (size_t)gm * K + sk;
    int br0 = tid >> 2;             // B rows (2 chunks/thread)
    int bk0 = (tid & 3) * 8;
    int br1 = (256 + tid) >> 2;
    int bk1 = bk0;
    const ushort_t* bptr0 = Bt + (size_t)(n0 + br0) * K + bk0;
    const ushort_t* bptr1 = Bt + (size_t)(n0 + br1) * K + bk1;

    // depth-2 prefetch registers
    uint4 av_a, av_b;
    float4 fa0_a, fa1_a, fa0_b, fa1_b;
    if (BNA) {
        fa0_a = *(const float4*)(aptrf);
        fa1_a = *(const float4*)(aptrf + 4);
        if (K > 32) {
            fa0_b = *(const float4*)(aptrf + 32);
            fa1_b = *(const float4*)(aptrf + 36);
        }
    } else {
        av_a = *(const uint4*)(aptr);
        if (K > 32) av_b = *(const uint4*)(aptr + 32);
    }
    uint4 bv0_a = *(const uint4*)(bptr0);
    uint4 bv1_a = *(const uint4*)(bptr1);
    uint4 bv0_b, bv1_b;
    if (K > 32) {
        bv0_b = *(const uint4*)(bptr0 + 32);
        bv1_b = *(const uint4*)(bptr1 + 32);
    }

    for (int k0 = 0; k0 < K; k0 += 32) {
        if (BNA) {
            int cb = k0 + sk;       // this iteration's channel base (L1-hot)
            float4 sc0 = *(const float4*)(bnsc + cb);
            float4 sc1 = *(const float4*)(bnsc + cb + 4);
            float4 sh0 = *(const float4*)(bnsh + cb);
            float4 sh1 = *(const float4*)(bnsh + cb + 4);
            float v0 = eluf(fa0_a.x * sc0.x + sh0.x);
            float v1 = eluf(fa0_a.y * sc0.y + sh0.y);
            float v2 = eluf(fa0_a.z * sc0.z + sh0.z);
            float v3 = eluf(fa0_a.w * sc0.w + sh0.w);
            float v4 = eluf(fa1_a.x * sc1.x + sh1.x);
            float v5 = eluf(fa1_a.y * sc1.y + sh1.y);
            float v6 = eluf(fa1_a.z * sc1.z + sh1.z);
            float v7 = eluf(fa1_a.w * sc1.w + sh1.w);
            *(uint4*)&As[sr * LDT + sk] = make_uint4(
                pack_bf16_rn(v0, v1), pack_bf16_rn(v2, v3),
                pack_bf16_rn(v4, v5), pack_bf16_rn(v6, v7));
        } else {
            *(uint4*)&As[sr * LDT + sk] = av_a;
        }
        *(uint4*)&Bs[br0 * LDT + bk0] = bv0_a;
        *(uint4*)&Bs[br1 * LDT + bk1] = bv1_a;
        __syncthreads();

        short8x af0 = *(const short8x*)&As[(wm +      c16) * LDT + quad * 8];
        short8x af1 = *(const short8x*)&As[(wm + 16 + c16) * LDT + quad * 8];
        short8x bf[4];
#pragma unroll
        for (int nt = 0; nt < 4; ++nt)
            bf[nt] = *(const short8x*)&Bs[(wn + nt * 16 + c16) * LDT + quad * 8];

        // shift pipeline; issue k+2's loads (~2 iterations in flight)
        if (BNA) {
            fa0_a = fa0_b; fa1_a = fa1_b;
            if (k0 + 64 < K) {
                fa0_b = *(const float4*)(aptrf + k0 + 64);
                fa1_b = *(const float4*)(aptrf + k0 + 68);
            }
        } else {
            av_a = av_b;
            if (k0 + 64 < K) av_b = *(const uint4*)(aptr + k0 + 64);
        }
        bv0_a = bv0_b; bv1_a = bv1_b;
        if (k0 + 64 < K) {
            bv0_b = *(const uint4*)(bptr0 + k0 + 64);
            bv1_b = *(const uint4*)(bptr1 + k0 + 64);
        }

#pragma unroll
        for (int nt = 0; nt < 4; ++nt) {
            acc[0][nt] = __builtin_amdgcn_mfma_f32_16x16x32_bf16(af0, bf[nt], acc[0][nt], 0, 0, 0);
            acc[1][nt] = __builtin_amdgcn_mfma_f32_16x16x32_bf16(af1, bf[nt], acc[1][nt], 0, 0, 0);
        }
        __syncthreads();
    }

    // ---- C store ----
#pragma unroll
    for (int mt = 0; mt < 2; ++mt) {
#pragma unroll
        for (int r2 = 0; r2 < 4; ++r2) {
            int row = m0 + wm + mt * 16 + quad * 4 + r2;
            if (row < M) {
#pragma unroll
                for (int nt = 0; nt < 4; ++nt) {
                    int col = n0 + wn + nt * 16 + c16;
                    Cb[(size_t)row * 512 + col] = f2bf(acc[mt][nt][r2]);
                }
            }
        }
    }

    // ---- fused logits epilogue ----
    float as_[4], ad_[4];
#pragma unroll
    for (int nt = 0; nt < 4; ++nt) {
        int colg = n0 + wn + nt * 16 + c16;     // global output column
        if (LOGIT == 4) {
            as_[nt] = aS[colg];                  // a_src flat over HC == col index
            ad_[nt] = aD[colg];
        } else {
            as_[nt] = (colg < OUTF_) ? aS[colg] : 0.f;
            ad_[nt] = (colg < OUTF_) ? aD[colg] : 0.f;
        }
    }
#pragma unroll
    for (int mt = 0; mt < 2; ++mt) {
#pragma unroll
        for (int r2 = 0; r2 < 4; ++r2) {
            float ps = acc[mt][0][r2] * as_[0] + acc[mt][1][r2] * as_[1]
                     + acc[mt][2][r2] * as_[2] + acc[mt][3][r2] * as_[3];
            float pd = acc[mt][0][r2] * ad_[0] + acc[mt][1][r2] * ad_[1]
                     + acc[mt][2][r2] * ad_[2] + acc[mt][3][r2] * ad_[3];
#pragma unroll
            for (int off = 1; off < 16; off <<= 1) {
                ps += __shfl_xor(ps, off);
                pd += __shfl_xor(pd, off);
            }
            if (c16 == 0) {
                int rl = wm + mt * 16 + quad * 4 + r2;   // 0..63
                sred[rl][wn >> 6] = ps;
                dred[rl][wn >> 6] = pd;
            }
        }
    }
    __syncthreads();
    if (tid < 64) {
        int row = m0 + tid;
        if (row < M) {
            float s = sred[tid][0] + sred[tid][1];
            float d = dred[tid][0] + dred[tid][1];
            if (LOGIT == 4) {
                int h = n0 >> 7;                 // block col-tile == head
                s_log[row * 4 + h] = s;
                d_log[row * 4 + h] = d;
            } else {
                atomicAdd(&s_log[row], s);
                atomicAdd(&d_log[row], d);
            }
        }
    }
}

// ---------------------------------------------------------------------------
// FUSED softmax+gather (no BN epilogue — R3 lesson).
//   out = (x_self + Σ_j w_j x_{src_j}) / (1 + Σ_j w_j),
//   w_j = exp(lrelu(s[src_j]+d[n]) - c0),  c0 = self logit (shift; w_self=1).
// Slicing (proven): slice pinned per XCD pair, 2.56 MB L2-resident.
// ---------------------------------------------------------------------------
__device__ __forceinline__ void acc8(float* acc, uint4 q, float w) {
    acc[0] += w * bf_lo(q.x); acc[1] += w * bf_hi(q.x);
    acc[2] += w * bf_lo(q.y); acc[3] += w * bf_hi(q.y);
    acc[4] += w * bf_lo(q.z); acc[5] += w * bf_hi(q.z);
    acc[6] += w * bf_lo(q.w); acc[7] += w * bf_hi(q.w);
}

template<int H>
__global__ __launch_bounds__(256) void gather_fused_kernel(
    const uint4* __restrict__ xpb4,     // [node][64]
    const int* __restrict__ offsets, const int* __restrict__ esrc,
    const float* __restrict__ s_log,    // [node][H]
    const float* __restrict__ d_log,    // [node][H]
    const float* __restrict__ bias,     // [OUTC]
    float* __restrict__ out,            // [node][ldo]
    int OUTC, int ldo)
{
    int id = blockIdx.x;
    int xcd = id & 7;
    int slice = xcd >> 1;                       // 0..3 — pinned per XCD pair
    int sub2 = xcd & 1;
    int wv = threadIdx.x >> 6;
    int node = (id >> 3) * 8 + sub2 * 4 + wv;
    if (node >= NNODES) return;
    int lane = threadIdx.x & 63;
    int esub = lane >> 4;                       // edge subgroup 0..3
    int l16 = lane & 15;
    int h = (H == 4) ? slice : 0;
    int rowoff = slice * 16 + l16;              // uint4 index within 64-wide row

    // node-constant attention terms
    float dh = d_log[node * H + h];
    float c0 = lrelu(s_log[node * H + h] + dh); // self-loop logit = shift

    float acc[8];
    float z;
    if (esub == 0) {
        // self loop: w = exp(c0 - c0) = 1
        uint4 p = xpb4[(size_t)node * 64 + rowoff];
        acc[0] = bf_lo(p.x); acc[1] = bf_hi(p.x);
        acc[2] = bf_lo(p.y); acc[3] = bf_hi(p.y);
        acc[4] = bf_lo(p.z); acc[5] = bf_hi(p.z);
        acc[6] = bf_lo(p.w); acc[7] = bf_hi(p.w);
        z = 1.0f;
    } else {
#pragma unroll
        for (int k = 0; k < 8; ++k) acc[k] = 0.f;
        z = 0.f;
    }

    int e0 = offsets[node], e1 = offsets[node + 1];
    int j = e0 + esub;
    for (; j + 12 < e1; j += 16) {
        int s0 = esrc[j], s1 = esrc[j + 4], s2 = esrc[j + 8], s3 = esrc[j + 12];
        uint4 q0 = xpb4[(size_t)s0 * 64 + rowoff];
        uint4 q1 = xpb4[(size_t)s1 * 64 + rowoff];
        uint4 q2 = xpb4[(size_t)s2 * 64 + rowoff];
        uint4 q3 = xpb4[(size_t)s3 * 64 + rowoff];
        float w0 = __expf(lrelu(s_log[s0 * H + h] + dh) - c0);
        float w1 = __expf(lrelu(s_log[s1 * H + h] + dh) - c0);
        float w2 = __expf(lrelu(s_log[s2 * H + h] + dh) - c0);
        float w3 = __expf(lrelu(s_log[s3 * H + h] + dh) - c0);
        acc8(acc, q0, w0);
        acc8(acc, q1, w1);
        acc8(acc, q2, w2);
        acc8(acc, q3, w3);
        z += w0 + w1 + w2 + w3;
    }
    for (; j < e1; j += 4) {
        int s0 = esrc[j];
        uint4 q0 = xpb4[(size_t)s0 * 64 + rowoff];
        float w0 = __expf(lrelu(s_log[s0 * H + h] + dh) - c0);
        acc8(acc, q0, w0);
        z += w0;
    }

    // combine the 4 edge subgroups
#pragma unroll
    for (int k = 0; k < 8; ++k) {
        acc[k] += __shfl_xor(acc[k], 16);
        acc[k] += __shfl_xor(acc[k], 32);
    }
    z += __shfl_xor(z, 16);
    z += __shfl_xor(z, 32);

    if (esub == 0) {
        float zi = 1.0f / z;
        int cbase = slice * 128 + l16 * 8;
        size_t ob = (size_t)node * ldo + cbase;
        if (cbase + 7 < OUTC) {
            float4 o0 = make_float4(acc[0] * zi + bias[cbase + 0], acc[1] * zi + bias[cbase + 1],
                                    acc[2] * zi + bias[cbase + 2], acc[3] * zi + bias[cbase + 3]);
            float4 o1 = make_float4(acc[4] * zi + bias[cbase + 4], acc[5] * zi + bias[cbase + 5],
                                    acc[6] * zi + bias[cbase + 6], acc[7] * zi + bias[cbase + 7]);
            *(float4*)(out + ob) = o0;
            *(float4*)(out + ob + 4) = o1;
        } else {
#pragma unroll
            for (int k = 0; k < 8; ++k) {
                int c = cbase + k;
                if (c < OUTC) out[ob + k] = acc[k] * zi + bias[c];
            }
        }
    }
}

// ---------------------------------------------------------------------------
// BN: stats (256 blocks, no fence, plain partial writes) + separate finalize
// (wave-per-channel, lane-parallel over banks). Kernel boundary = the fence.
// ---------------------------------------------------------------------------
#define BNB 256     // stats blocks (= partial banks)

__global__ __launch_bounds__(512) void bn_stats_kernel(const float* __restrict__ h,
                                                       float* __restrict__ psum,
                                                       float* __restrict__ psumsq) {
    int c = threadIdx.x;  // 512 = one channel
    int b = blockIdx.x;   // BNB
    float sm = 0.f, sq = 0.f;
#pragma unroll 4
    for (int r2 = b; r2 < NNODES; r2 += BNB) {
        float v = h[(size_t)r2 * 512 + c];
        sm += v;
        sq += v * v;
    }
    psum[b * 512 + c] = sm;
    psumsq[b * 512 + c] = sq;
}

// 64 blocks x 8 waves: one wave per channel; lane l sums banks l, l+64, ...
__global__ __launch_bounds__(512) void bn_finalize_kernel(const float* __restrict__ psum,
                                                          const float* __restrict__ psumsq,
                                                          const float* __restrict__ gamma,
                                                          const float* __restrict__ beta,
                                                          float* __restrict__ scale,
                                                          float* __restrict__ shift) {
    int t = threadIdx.x;
    int wv = t >> 6, lane = t & 63;
    int c = blockIdx.x * 8 + wv;          // 64 blocks * 8 waves = 512 channels
    float s = 0.f, q = 0.f;
#pragma unroll
    for (int k = 0; k < BNB / 64; ++k) {  // 4 banks per lane
        int b = lane + k * 64;
        s += psum[b * 512 + c];
        q += psumsq[b * 512 + c];
    }
#pragma unroll
    for (int off = 32; off > 0; off >>= 1) {
        s += __shfl_xor(s, off);
        q += __shfl_xor(q, off);
    }
    if (lane == 0) {
        const float invN = 1.0f / (float)NNODES;
        float mu = s * invN;
        float var = q * invN - mu * mu;
        float sc = gamma[c] * rsqrtf(var + BN_EPS);
        scale[c] = sc;
        shift[c] = beta[c] - mu * sc;
    }
}

// ---------------------------------------------------------------------------
// launch — 14 dispatches
// ---------------------------------------------------------------------------
extern "C" void kernel_launch(void* const* d_in, const int* in_sizes, int n_in,
                              void* d_out, int out_size, void* d_ws, size_t ws_size,
                              hipStream_t stream) {
    const float* x      = (const float*)d_in[0];
    const int*   ei     = (const int*)d_in[1];
    const float* W1     = (const float*)d_in[2];
    const float* a_src1 = (const float*)d_in[3];
    const float* a_dst1 = (const float*)d_in[4];
    const float* b1     = (const float*)d_in[5];
    const float* g1     = (const float*)d_in[6];
    const float* be1    = (const float*)d_in[7];
    const float* W2     = (const float*)d_in[8];
    const float* a_src2 = (const float*)d_in[9];
    const float* a_dst2 = (const float*)d_in[10];
    const float* b2     = (const float*)d_in[11];
    const float* g2     = (const float*)d_in[12];
    const float* be2    = (const float*)d_in[13];
    const float* W3     = (const float*)d_in[14];
    const float* a_src3 = (const float*)d_in[15];
    const float* a_dst3 = (const float*)d_in[16];
    const float* b3     = (const float*)d_in[17];
    float* out = (float*)d_out;

    const int* e_src = ei;           // edge_index[0]
    const int* e_dst = ei + NEDGES;  // edge_index[1]

    // ---- workspace layout ----
    char* w = (char*)d_ws;
    ushort_t* x_bf = (ushort_t*)w;
    float*    hbuf = (float*)w;                               // alias after L1 GEMM
    w += (size_t)NNODES * INF_ * sizeof(ushort_t);            // 25.6 MB
    uint_t* xpb = (uint_t*)w;  w += (size_t)NNODES * HC_ * sizeof(ushort_t);
    ushort_t* Wt1 = (ushort_t*)w; w += (size_t)HC_ * INF_ * sizeof(ushort_t);
    ushort_t* Wt2 = (ushort_t*)w; w += (size_t)HC_ * HC_ * sizeof(ushort_t);
    ushort_t* Wt3 = (ushort_t*)w; w += (size_t)HC_ * HC_ * sizeof(ushort_t);
    int* counts  = (int*)w;    w += NNODES * sizeof(int);
    float* s_log = (float*)w;  w += NNODES * HEADS_ * sizeof(float);
    float* d_log = (float*)w;  w += NNODES * HEADS_ * sizeof(float);
    float* s3_log = (float*)w; w += NNODES * sizeof(float);   // contiguous zero range
    float* d3_log = (float*)w; w += NNODES * sizeof(float);
    float* bnscale = (float*)w; w += HC_ * sizeof(float);
    float* bnshift = (float*)w; w += HC_ * sizeof(float);
    float* psum  = (float*)w;  w += (size_t)BNB * HC_ * sizeof(float);
    float* psumsq= (float*)w;  w += (size_t)BNB * HC_ * sizeof(float);
    int* offsets = (int*)w;    w += (NNODES + 1) * sizeof(int);
    int* cursor  = (int*)w;    w += NNODES * sizeof(int);
    int* esrc    = (int*)w;    w += NEDGES * sizeof(int);

    const int ggBlocks = (HC_ / 128) * ((NNODES + 63) / 64);   // 628, 1-D + swizzle
    const int gaGrid = ((NNODES + 7) / 8) * 8;       // 10000 (sliced gather)

    {
        int TOT = CVX + CN1 + CN2 + CN3 + CZC + CZ3;
        convall_kernel<<<(TOT + 255) / 256, 256, 0, stream>>>(x, W1, W2, W3,
            x_bf, Wt1, Wt2, Wt3, (uint4*)counts, (uint4*)s3_log);
    }
    count_kernel<<<(NEDGES + 255) / 256, 256, 0, stream>>>(e_dst, counts, NEDGES);
    scan_fused_kernel<<<1, 1024, 0, stream>>>(counts, offsets, cursor, NNODES);
    scatter_kernel<<<(NEDGES + 255) / 256, 256, 0, stream>>>(e_src, e_dst, cursor, esrc, NEDGES);

    // ---- Layer 1 ----
    gemm_kernel<4, false><<<ggBlocks, 256, 0, stream>>>(x_bf, Wt1, (ushort_t*)xpb,
        nullptr, nullptr, a_src1, a_dst1, s_log, d_log, NNODES, INF_);
    gather_fused_kernel<HEADS_><<<gaGrid, 256, 0, stream>>>((const uint4*)xpb, offsets, esrc,
        s_log, d_log, b1, hbuf, HC_, HC_);
    bn_stats_kernel<<<BNB, 512, 0, stream>>>(hbuf, psum, psumsq);
    bn_finalize_kernel<<<64, 512, 0, stream>>>(psum, psumsq, g1, be1, bnscale, bnshift);

    // ---- Layer 2 (BN1+ELU applied inline on A staging) ----
    gemm_kernel<4, true><<<ggBlocks, 256, 0, stream>>>(hbuf, Wt2, (ushort_t*)xpb,
        bnscale, bnshift, a_src2, a_dst2, s_log, d_log, NNODES, HC_);
    gather_fused_kernel<HEADS_><<<gaGrid, 256, 0, stream>>>((const uint4*)xpb, offsets, esrc,
        s_log, d_log, b2, hbuf, HC_, HC_);
    bn_stats_kernel<<<BNB, 512, 0, stream>>>(hbuf, psum, psumsq);
    bn_finalize_kernel<<<64, 512, 0, stream>>>(psum, psumsq, g2, be2, bnscale, bnshift);

    // ---- Layer 3 (H=1, N=500; BN2+ELU inline; logits accumulate into zeroed s3/d3) ----
    gemm_kernel<1, true><<<ggBlocks, 256, 0, stream>>>(hbuf, Wt3, (ushort_t*)xpb,
        bnscale, bnshift, a_src3, a_dst3, s3_log, d3_log, NNODES, HC_);
    gather_fused_kernel<1><<<gaGrid, 256, 0, stream>>>((const uint4*)xpb, offsets, esrc,
        s3_log, d3_log, b3, out, OUTF_, OUTF_);
}